// Round 18
// baseline (34.618 us; speedup 1.0000x reference)
//
#include <hip/hip_runtime.h>
#include <math.h>

#define NTHR 256
#define B_ 4
#define F_ 512
#define N_ 1024
#define V_ 4
#define GSTR (F_ * N_)               // 524288 points per batch
#define QPB  (GSTR / 4)              // 131072 quads per batch
#define NBLK (QPB / NTHR * 2)        // 1024 blocks: batch-pair x 512 quad-groups

struct Partial {                     // 64 B, all f32
  float sum_diff2, sum_dist, sum_acc2, cnt;
  float gmin[3], gmax[3], pmin[3], pmax[3];
};

__global__ __launch_bounds__(NTHR) void loss_main(
    const float* __restrict__ pred, const float* __restrict__ gt,
    const int* __restrict__ vis, const float* __restrict__ P,
    const float* __restrict__ tracks, Partial* __restrict__ partials)
{
  __shared__ float sP[B_ * V_ * 12];          // all 16 mats
  __shared__ Partial sw[NTHR / 64];

  // XCD-bijective swizzle (1024 % 8 == 0): 128 consecutive blocks per XCD
  const int bid = ((blockIdx.x & 7) << 7) + (blockIdx.x >> 3);
  const int t = threadIdx.x;
  const int half = bid >> 9;                  // batch pair: {0,1} or {2,3}
  const int qg = ((bid & 511) << 8) + t;      // quad index within batch
  const int pib = qg << 2;                    // first point-in-batch of quad
  const int f = pib >> 10;                    // frame (quad-uniform)

  if (t < B_ * V_ * 12) sP[t] = P[t];         // P is [V][B][3][4] = 192 floats
  __syncthreads();

  // frame-uniform clamped neighbor offsets (in points) and temporal mask
  const int d1 = (f + 1 < F_) ? N_ : 0;
  const int d2 = (f + 2 < F_) ? 2 * N_ : 0;
  const float am = (f < F_ - 2) ? 1.0f : 0.0f;

  float sum_diff2 = 0.0f, sum_dist = 0.0f, sum_acc2 = 0.0f, cntf = 0.0f;
  float gmin[3] = { INFINITY,  INFINITY,  INFINITY};
  float gmax[3] = {-INFINITY, -INFINITY, -INFINITY};
  float pmin[3] = { INFINITY,  INFINITY,  INFINITY};
  float pmax[3] = {-INFINITY, -INFINITY, -INFINITY};

  for (int bi = 0; bi < 2; ++bi) {
    const int b = (half << 1) + bi;
    const size_t e0 = (size_t)b * GSTR + pib;     // first point of quad

    // ---- all loads up front: 21 x 16B, independent, coalesced
    const float4* pp4 = (const float4*)(pred + e0 * 3);
    const float4 pA = pp4[0], pB = pp4[1], pC = pp4[2];
    const float4* gp4 = (const float4*)(gt + e0 * 3);
    const float4 gA = gp4[0], gB = gp4[1], gC = gp4[2];
    const int4 vv = *(const int4*)(vis + e0);
    const float4* q14 = (const float4*)(pred + (e0 + d1) * 3);
    const float4 aA = q14[0], aB = q14[1], aC = q14[2];
    const float4* q24 = (const float4*)(pred + (e0 + d2) * 3);
    const float4 cA = q24[0], cB = q24[1], cC = q24[2];
    const float4* tp0 = (const float4*)(tracks + (((size_t)(0 * B_ + b) << 20) + ((size_t)pib << 1)));
    const float4* tp1 = (const float4*)(tracks + (((size_t)(1 * B_ + b) << 20) + ((size_t)pib << 1)));
    const float4* tp2 = (const float4*)(tracks + (((size_t)(2 * B_ + b) << 20) + ((size_t)pib << 1)));
    const float4* tp3 = (const float4*)(tracks + (((size_t)(3 * B_ + b) << 20) + ((size_t)pib << 1)));
    const float4 t0a = tp0[0], t0b = tp0[1];
    const float4 t1a = tp1[0], t1b = tp1[1];
    const float4 t2a = tp2[0], t2b = tp2[1];
    const float4 t3a = tp3[0], t3b = tp3[1];

    // ---- unswizzle quads
    const float px[4] = {pA.x, pA.w, pB.z, pC.y};
    const float py[4] = {pA.y, pB.x, pB.w, pC.z};
    const float pz[4] = {pA.z, pB.y, pC.x, pC.w};
    const float gx[4] = {gA.x, gA.w, gB.z, gC.y};
    const float gy[4] = {gA.y, gB.x, gB.w, gC.z};
    const float gz[4] = {gA.z, gB.y, gC.x, gC.w};
    const int vm[4] = {vv.x, vv.y, vv.z, vv.w};
    const float ax[4] = {aA.x, aA.w, aB.z, aC.y};
    const float ay[4] = {aA.y, aB.x, aB.w, aC.z};
    const float az[4] = {aA.z, aB.y, aC.x, aC.w};
    const float cx[4] = {cA.x, cA.w, cB.z, cC.y};
    const float cy[4] = {cA.y, cB.x, cB.w, cC.z};
    const float cz[4] = {cA.z, cB.y, cC.x, cC.w};
    const float tx[V_][4] = {{t0a.x, t0a.z, t0b.x, t0b.z},
                             {t1a.x, t1a.z, t1b.x, t1b.z},
                             {t2a.x, t2a.z, t2b.x, t2b.z},
                             {t3a.x, t3a.z, t3b.x, t3b.z}};
    const float ty[V_][4] = {{t0a.y, t0a.w, t0b.y, t0b.w},
                             {t1a.y, t1a.w, t1b.y, t1b.w},
                             {t2a.y, t2a.w, t2b.y, t2b.w},
                             {t3a.y, t3a.w, t3b.y, t3b.w}};

    // ---- compute 4 points (branchless)
#pragma unroll
    for (int i = 0; i < 4; ++i) {
      const float vmf = vm[i] ? 1.0f : 0.0f;
      const float dd0 = px[i] - gx[i], dd1 = py[i] - gy[i], dd2 = pz[i] - gz[i];
      sum_diff2 += vmf * (dd0 * dd0 + dd1 * dd1 + dd2 * dd2);
      cntf += vmf;
      gmin[0] = fminf(gmin[0], vm[i] ? gx[i] :  INFINITY);
      gmax[0] = fmaxf(gmax[0], vm[i] ? gx[i] : -INFINITY);
      gmin[1] = fminf(gmin[1], vm[i] ? gy[i] :  INFINITY);
      gmax[1] = fmaxf(gmax[1], vm[i] ? gy[i] : -INFINITY);
      gmin[2] = fminf(gmin[2], vm[i] ? gz[i] :  INFINITY);
      gmax[2] = fmaxf(gmax[2], vm[i] ? gz[i] : -INFINITY);
      pmin[0] = fminf(pmin[0], px[i]); pmax[0] = fmaxf(pmax[0], px[i]);
      pmin[1] = fminf(pmin[1], py[i]); pmax[1] = fmaxf(pmax[1], py[i]);
      pmin[2] = fminf(pmin[2], pz[i]); pmax[2] = fmaxf(pmax[2], pz[i]);

      const float a0 = cx[i] - 2.0f * ax[i] + px[i];
      const float a1 = cy[i] - 2.0f * ay[i] + py[i];
      const float a2 = cz[i] - 2.0f * az[i] + pz[i];
      sum_acc2 += am * (a0 * a0 + a1 * a1 + a2 * a2);

#pragma unroll
      for (int v = 0; v < V_; ++v) {
        const float* Pm = sP + (v * B_ + b) * 12;
        const float h0 = Pm[0] * px[i] + Pm[1] * py[i] + Pm[2]  * pz[i] + Pm[3];
        const float h1 = Pm[4] * px[i] + Pm[5] * py[i] + Pm[6]  * pz[i] + Pm[7];
        const float h2 = Pm[8] * px[i] + Pm[9] * py[i] + Pm[10] * pz[i] + Pm[11];
        const float inv = __builtin_amdgcn_rcpf(h2 + 1e-10f);
        const float dx = h0 * inv - tx[v][i];
        const float dy = h1 * inv - ty[v][i];
        sum_dist += dx * dx + dy * dy;
      }
    }
  }

  // ---- wave shuffle reduction (deterministic tree), amortized over 8 pts
#pragma unroll
  for (int o = 32; o > 0; o >>= 1) {
    sum_diff2 += __shfl_down(sum_diff2, o);
    sum_dist  += __shfl_down(sum_dist,  o);
    sum_acc2  += __shfl_down(sum_acc2,  o);
    cntf      += __shfl_down(cntf,      o);
#pragma unroll
    for (int k = 0; k < 3; ++k) {
      gmin[k] = fminf(gmin[k], __shfl_down(gmin[k], o));
      gmax[k] = fmaxf(gmax[k], __shfl_down(gmax[k], o));
      pmin[k] = fminf(pmin[k], __shfl_down(pmin[k], o));
      pmax[k] = fmaxf(pmax[k], __shfl_down(pmax[k], o));
    }
  }

  const int wave = t >> 6, lane = t & 63;
  if (lane == 0) {
    Partial p;
    p.sum_diff2 = sum_diff2; p.sum_dist = sum_dist;
    p.sum_acc2  = sum_acc2;  p.cnt      = cntf;
#pragma unroll
    for (int k = 0; k < 3; ++k) {
      p.gmin[k] = gmin[k]; p.gmax[k] = gmax[k];
      p.pmin[k] = pmin[k]; p.pmax[k] = pmax[k];
    }
    sw[wave] = p;
  }
  __syncthreads();
  if (t == 0) {
    Partial p = sw[0];
#pragma unroll
    for (int w = 1; w < NTHR / 64; ++w) {
      p.sum_diff2 += sw[w].sum_diff2; p.sum_dist += sw[w].sum_dist;
      p.sum_acc2  += sw[w].sum_acc2;  p.cnt      += sw[w].cnt;
#pragma unroll
      for (int k = 0; k < 3; ++k) {
        p.gmin[k] = fminf(p.gmin[k], sw[w].gmin[k]);
        p.gmax[k] = fmaxf(p.gmax[k], sw[w].gmax[k]);
        p.pmin[k] = fminf(p.pmin[k], sw[w].pmin[k]);
        p.pmax[k] = fmaxf(p.pmax[k], sw[w].pmax[k]);
      }
    }
    partials[bid] = p;
  }
}

__global__ __launch_bounds__(NTHR) void loss_final(
    const Partial* __restrict__ partials, float* __restrict__ out)
{
  float sum_diff2 = 0.0f, sum_dist = 0.0f, sum_acc2 = 0.0f, cnt = 0.0f;
  float gmin[3] = { INFINITY,  INFINITY,  INFINITY};
  float gmax[3] = {-INFINITY, -INFINITY, -INFINITY};
  float pmin[3] = { INFINITY,  INFINITY,  INFINITY};
  float pmax[3] = {-INFINITY, -INFINITY, -INFINITY};

  const int tid = threadIdx.x;
  for (int i = tid; i < NBLK; i += NTHR) {   // fixed order -> deterministic
    const Partial p = partials[i];
    sum_diff2 += p.sum_diff2; sum_dist += p.sum_dist;
    sum_acc2  += p.sum_acc2;  cnt      += p.cnt;
#pragma unroll
    for (int k = 0; k < 3; ++k) {
      gmin[k] = fminf(gmin[k], p.gmin[k]); gmax[k] = fmaxf(gmax[k], p.gmax[k]);
      pmin[k] = fminf(pmin[k], p.pmin[k]); pmax[k] = fmaxf(pmax[k], p.pmax[k]);
    }
  }

#pragma unroll
  for (int o = 32; o > 0; o >>= 1) {
    sum_diff2 += __shfl_down(sum_diff2, o);
    sum_dist  += __shfl_down(sum_dist,  o);
    sum_acc2  += __shfl_down(sum_acc2,  o);
    cnt       += __shfl_down(cnt,       o);
#pragma unroll
    for (int k = 0; k < 3; ++k) {
      gmin[k] = fminf(gmin[k], __shfl_down(gmin[k], o));
      gmax[k] = fmaxf(gmax[k], __shfl_down(gmax[k], o));
      pmin[k] = fminf(pmin[k], __shfl_down(pmin[k], o));
      pmax[k] = fmaxf(pmax[k], __shfl_down(pmax[k], o));
    }
  }

  __shared__ Partial sw[NTHR / 64];
  const int lane = tid & 63;
  const int wave = tid >> 6;
  if (lane == 0) {
    Partial p;
    p.sum_diff2 = sum_diff2; p.sum_dist = sum_dist;
    p.sum_acc2  = sum_acc2;  p.cnt      = cnt;
#pragma unroll
    for (int k = 0; k < 3; ++k) {
      p.gmin[k] = gmin[k]; p.gmax[k] = gmax[k];
      p.pmin[k] = pmin[k]; p.pmax[k] = pmax[k];
    }
    sw[wave] = p;
  }
  __syncthreads();

  if (tid == 0) {
    Partial p = sw[0];
#pragma unroll
    for (int w = 1; w < NTHR / 64; ++w) {
      p.sum_diff2 += sw[w].sum_diff2; p.sum_dist += sw[w].sum_dist;
      p.sum_acc2  += sw[w].sum_acc2;  p.cnt      += sw[w].cnt;
#pragma unroll
      for (int k = 0; k < 3; ++k) {
        p.gmin[k] = fminf(p.gmin[k], sw[w].gmin[k]);
        p.gmax[k] = fmaxf(p.gmax[k], sw[w].gmax[k]);
        p.pmin[k] = fminf(p.pmin[k], sw[w].pmin[k]);
        p.pmax[k] = fmaxf(p.pmax[k], sw[w].pmax[k]);
      }
    }

    double sr = -INFINITY;
#pragma unroll
    for (int k = 0; k < 3; ++k) sr = fmax(sr, (double)p.gmax[k] - (double)p.gmin[k]);
    sr += 1e-6;
    const double recon = (double)p.sum_diff2 / fmax((double)p.cnt * 3.0, 1.0) / (sr * sr);

    const double ident = (double)p.sum_dist / 224.0 / ((double)V_ * B_ * F_ * N_ * 2.0);

    double st = -INFINITY;
#pragma unroll
    for (int k = 0; k < 3; ++k) st = fmax(st, (double)p.pmax[k] - (double)p.pmin[k]);
    st += 1e-6;
    const double tloss = (double)p.sum_acc2 / ((double)B_ * (F_ - 2) * N_);
    const double temp = tloss / (st * st);

    const double total = recon + ident + 0.5 * temp;
    out[0] = (float)total;
    out[1] = (float)recon;
    out[2] = (float)ident;
    out[3] = (float)temp;
  }
}

extern "C" void kernel_launch(void* const* d_in, const int* in_sizes, int n_in,
                              void* d_out, int out_size, void* d_ws, size_t ws_size,
                              hipStream_t stream) {
  const float* pred   = (const float*)d_in[0];
  const float* gt     = (const float*)d_in[1];
  const int*   vis    = (const int*)d_in[2];
  const float* P      = (const float*)d_in[3];
  const float* tracks = (const float*)d_in[4];
  float* out = (float*)d_out;
  Partial* partials = (Partial*)d_ws;   // 1024 * 64 B = 64 KB

  loss_main<<<NBLK, NTHR, 0, stream>>>(pred, gt, vis, P, tracks, partials);
  loss_final<<<1, NTHR, 0, stream>>>(partials, out);
}

// Round 19
// 31.249 us; speedup vs baseline: 1.1078x; 1.1078x over previous
//
#include <hip/hip_runtime.h>
#include <math.h>

#define NTHR 256
#define CF   8                        // frames walked per thread
#define NBLK (B_ * (F_ / CF) * 4)     // 4*64*4 = 1024
#define B_ 4
#define F_ 512
#define N_ 1024
#define V_ 4

struct Partial {                      // 64 B, all f32
  float sum_diff2, sum_dist, sum_acc2, cnt;
  float gmin[3], gmax[3], pmin[3], pmax[3];
};

__global__ __launch_bounds__(NTHR) void loss_main(
    const float* __restrict__ pred, const float* __restrict__ gt,
    const int* __restrict__ vis, const float* __restrict__ P,
    const float* __restrict__ tracks, Partial* __restrict__ partials)
{
  __shared__ Partial sw[NTHR / 64];

  // XCD-bijective swizzle (1024 % 8 == 0): 128 consecutive blocks per XCD
  const int bid = ((blockIdx.x & 7) << 7) + (blockIdx.x >> 3);
  const int b  = __builtin_amdgcn_readfirstlane(bid >> 8);   // 256 blocks/batch
  const int fc = (bid >> 2) & 63;
  const int qr = bid & 3;
  const int f0 = fc << 3;
  const int t  = threadIdx.x;
  const int n  = (qr << 8) + t;

  // projection matrices via uniform (scalar) loads
  float Pmv[V_][12];
#pragma unroll
  for (int v = 0; v < V_; ++v)
#pragma unroll
    for (int j = 0; j < 12; ++j)
      Pmv[v][j] = P[(v * B_ + b) * 12 + j];

  // sliding pred window: rows f0, f0+1 in registers
  const size_t colOff = (size_t)n * 3;
  const float* pr0 = pred + ((size_t)(b * F_ + f0) * N_) * 3 + colOff;
  float p0x = pr0[0], p0y = pr0[1], p0z = pr0[2];
  const float* pr1 = pred + ((size_t)(b * F_ + f0 + 1) * N_) * 3 + colOff;
  float p1x = pr1[0], p1y = pr1[1], p1z = pr1[2];

  float sum_diff2 = 0.0f, sum_dist = 0.0f, sum_acc2 = 0.0f, cntf = 0.0f;
  float gmin[3] = { INFINITY,  INFINITY,  INFINITY};
  float gmax[3] = {-INFINITY, -INFINITY, -INFINITY};
  float pmin[3] = { INFINITY,  INFINITY,  INFINITY};
  float pmax[3] = {-INFINITY, -INFINITY, -INFINITY};

#pragma unroll 2
  for (int i = 0; i < CF; ++i) {
    const int fi = f0 + i;
    const int r2 = (fi + 2 < F_) ? fi + 2 : F_ - 1;   // clamped (acc masked)

    // ---- loads for this frame (independent, coalesced dword streams)
    const float* p2p = pred + ((size_t)(b * F_ + r2) * N_) * 3 + colOff;
    const float p2x = p2p[0], p2y = p2p[1], p2z = p2p[2];

    const float* gp = gt + ((size_t)(b * F_ + fi) * N_) * 3 + colOff;
    const float gx = gp[0], gy = gp[1], gz = gp[2];

    const int vm = vis[(size_t)(b * F_ + fi) * N_ + n];

    const float2 tk0 = *(const float2*)(tracks + (((size_t)(0 * B_ + b) * F_ + fi) * N_ + n) * 2);
    const float2 tk1 = *(const float2*)(tracks + (((size_t)(1 * B_ + b) * F_ + fi) * N_ + n) * 2);
    const float2 tk2 = *(const float2*)(tracks + (((size_t)(2 * B_ + b) * F_ + fi) * N_ + n) * 2);
    const float2 tk3 = *(const float2*)(tracks + (((size_t)(3 * B_ + b) * F_ + fi) * N_ + n) * 2);

    // ---- current point is the window head
    const float px = p0x, py = p0y, pz = p0z;

    pmin[0] = fminf(pmin[0], px); pmax[0] = fmaxf(pmax[0], px);
    pmin[1] = fminf(pmin[1], py); pmax[1] = fmaxf(pmax[1], py);
    pmin[2] = fminf(pmin[2], pz); pmax[2] = fmaxf(pmax[2], pz);

    const float vmf = vm ? 1.0f : 0.0f;
    const float dd0 = px - gx, dd1 = py - gy, dd2 = pz - gz;
    sum_diff2 += vmf * (dd0 * dd0 + dd1 * dd1 + dd2 * dd2);
    cntf += vmf;
    gmin[0] = fminf(gmin[0], vm ? gx :  INFINITY);
    gmax[0] = fmaxf(gmax[0], vm ? gx : -INFINITY);
    gmin[1] = fminf(gmin[1], vm ? gy :  INFINITY);
    gmax[1] = fmaxf(gmax[1], vm ? gy : -INFINITY);
    gmin[2] = fminf(gmin[2], vm ? gz :  INFINITY);
    gmax[2] = fmaxf(gmax[2], vm ? gz : -INFINITY);

    const float am = (fi < F_ - 2) ? 1.0f : 0.0f;
    const float a0 = p2x - 2.0f * p1x + px;
    const float a1 = p2y - 2.0f * p1y + py;
    const float a2 = p2z - 2.0f * p1z + pz;
    sum_acc2 += am * (a0 * a0 + a1 * a1 + a2 * a2);

    const float2 tks[V_] = {tk0, tk1, tk2, tk3};
#pragma unroll
    for (int v = 0; v < V_; ++v) {
      const float h0 = Pmv[v][0] * px + Pmv[v][1] * py + Pmv[v][2]  * pz + Pmv[v][3];
      const float h1 = Pmv[v][4] * px + Pmv[v][5] * py + Pmv[v][6]  * pz + Pmv[v][7];
      const float h2 = Pmv[v][8] * px + Pmv[v][9] * py + Pmv[v][10] * pz + Pmv[v][11];
      const float inv = __builtin_amdgcn_rcpf(h2 + 1e-10f);
      const float dx = h0 * inv - tks[v].x;
      const float dy = h1 * inv - tks[v].y;
      sum_dist += dx * dx + dy * dy;
    }

    // ---- slide window
    p0x = p1x; p0y = p1y; p0z = p1z;
    p1x = p2x; p1y = p2y; p1z = p2z;
  }

  // ---- wave shuffle reduction (deterministic tree), amortized over 8 pts
#pragma unroll
  for (int o = 32; o > 0; o >>= 1) {
    sum_diff2 += __shfl_down(sum_diff2, o);
    sum_dist  += __shfl_down(sum_dist,  o);
    sum_acc2  += __shfl_down(sum_acc2,  o);
    cntf      += __shfl_down(cntf,      o);
#pragma unroll
    for (int k = 0; k < 3; ++k) {
      gmin[k] = fminf(gmin[k], __shfl_down(gmin[k], o));
      gmax[k] = fmaxf(gmax[k], __shfl_down(gmax[k], o));
      pmin[k] = fminf(pmin[k], __shfl_down(pmin[k], o));
      pmax[k] = fmaxf(pmax[k], __shfl_down(pmax[k], o));
    }
  }

  const int wave = t >> 6, lane = t & 63;
  if (lane == 0) {
    Partial p;
    p.sum_diff2 = sum_diff2; p.sum_dist = sum_dist;
    p.sum_acc2  = sum_acc2;  p.cnt      = cntf;
#pragma unroll
    for (int k = 0; k < 3; ++k) {
      p.gmin[k] = gmin[k]; p.gmax[k] = gmax[k];
      p.pmin[k] = pmin[k]; p.pmax[k] = pmax[k];
    }
    sw[wave] = p;
  }
  __syncthreads();
  if (t == 0) {
    Partial p = sw[0];
#pragma unroll
    for (int w = 1; w < NTHR / 64; ++w) {
      p.sum_diff2 += sw[w].sum_diff2; p.sum_dist += sw[w].sum_dist;
      p.sum_acc2  += sw[w].sum_acc2;  p.cnt      += sw[w].cnt;
#pragma unroll
      for (int k = 0; k < 3; ++k) {
        p.gmin[k] = fminf(p.gmin[k], sw[w].gmin[k]);
        p.gmax[k] = fmaxf(p.gmax[k], sw[w].gmax[k]);
        p.pmin[k] = fminf(p.pmin[k], sw[w].pmin[k]);
        p.pmax[k] = fmaxf(p.pmax[k], sw[w].pmax[k]);
      }
    }
    partials[bid] = p;
  }
}

__global__ __launch_bounds__(NTHR) void loss_final(
    const Partial* __restrict__ partials, float* __restrict__ out)
{
  float sum_diff2 = 0.0f, sum_dist = 0.0f, sum_acc2 = 0.0f, cnt = 0.0f;
  float gmin[3] = { INFINITY,  INFINITY,  INFINITY};
  float gmax[3] = {-INFINITY, -INFINITY, -INFINITY};
  float pmin[3] = { INFINITY,  INFINITY,  INFINITY};
  float pmax[3] = {-INFINITY, -INFINITY, -INFINITY};

  const int tid = threadIdx.x;
  for (int i = tid; i < NBLK; i += NTHR) {   // fixed order -> deterministic
    const Partial p = partials[i];
    sum_diff2 += p.sum_diff2; sum_dist += p.sum_dist;
    sum_acc2  += p.sum_acc2;  cnt      += p.cnt;
#pragma unroll
    for (int k = 0; k < 3; ++k) {
      gmin[k] = fminf(gmin[k], p.gmin[k]); gmax[k] = fmaxf(gmax[k], p.gmax[k]);
      pmin[k] = fminf(pmin[k], p.pmin[k]); pmax[k] = fmaxf(pmax[k], p.pmax[k]);
    }
  }

#pragma unroll
  for (int o = 32; o > 0; o >>= 1) {
    sum_diff2 += __shfl_down(sum_diff2, o);
    sum_dist  += __shfl_down(sum_dist,  o);
    sum_acc2  += __shfl_down(sum_acc2,  o);
    cnt       += __shfl_down(cnt,       o);
#pragma unroll
    for (int k = 0; k < 3; ++k) {
      gmin[k] = fminf(gmin[k], __shfl_down(gmin[k], o));
      gmax[k] = fmaxf(gmax[k], __shfl_down(gmax[k], o));
      pmin[k] = fminf(pmin[k], __shfl_down(pmin[k], o));
      pmax[k] = fmaxf(pmax[k], __shfl_down(pmax[k], o));
    }
  }

  __shared__ Partial sw[NTHR / 64];
  const int lane = tid & 63;
  const int wave = tid >> 6;
  if (lane == 0) {
    Partial p;
    p.sum_diff2 = sum_diff2; p.sum_dist = sum_dist;
    p.sum_acc2  = sum_acc2;  p.cnt      = cnt;
#pragma unroll
    for (int k = 0; k < 3; ++k) {
      p.gmin[k] = gmin[k]; p.gmax[k] = gmax[k];
      p.pmin[k] = pmin[k]; p.pmax[k] = pmax[k];
    }
    sw[wave] = p;
  }
  __syncthreads();

  if (tid == 0) {
    Partial p = sw[0];
#pragma unroll
    for (int w = 1; w < NTHR / 64; ++w) {
      p.sum_diff2 += sw[w].sum_diff2; p.sum_dist += sw[w].sum_dist;
      p.sum_acc2  += sw[w].sum_acc2;  p.cnt      += sw[w].cnt;
#pragma unroll
      for (int k = 0; k < 3; ++k) {
        p.gmin[k] = fminf(p.gmin[k], sw[w].gmin[k]);
        p.gmax[k] = fmaxf(p.gmax[k], sw[w].gmax[k]);
        p.pmin[k] = fminf(p.pmin[k], sw[w].pmin[k]);
        p.pmax[k] = fmaxf(p.pmax[k], sw[w].pmax[k]);
      }
    }

    double sr = -INFINITY;
#pragma unroll
    for (int k = 0; k < 3; ++k) sr = fmax(sr, (double)p.gmax[k] - (double)p.gmin[k]);
    sr += 1e-6;
    const double recon = (double)p.sum_diff2 / fmax((double)p.cnt * 3.0, 1.0) / (sr * sr);

    const double ident = (double)p.sum_dist / 224.0 / ((double)V_ * B_ * F_ * N_ * 2.0);

    double st = -INFINITY;
#pragma unroll
    for (int k = 0; k < 3; ++k) st = fmax(st, (double)p.pmax[k] - (double)p.pmin[k]);
    st += 1e-6;
    const double tloss = (double)p.sum_acc2 / ((double)B_ * (F_ - 2) * N_);
    const double temp = tloss / (st * st);

    const double total = recon + ident + 0.5 * temp;
    out[0] = (float)total;
    out[1] = (float)recon;
    out[2] = (float)ident;
    out[3] = (float)temp;
  }
}

extern "C" void kernel_launch(void* const* d_in, const int* in_sizes, int n_in,
                              void* d_out, int out_size, void* d_ws, size_t ws_size,
                              hipStream_t stream) {
  const float* pred   = (const float*)d_in[0];
  const float* gt     = (const float*)d_in[1];
  const int*   vis    = (const int*)d_in[2];
  const float* P      = (const float*)d_in[3];
  const float* tracks = (const float*)d_in[4];
  float* out = (float*)d_out;
  Partial* partials = (Partial*)d_ws;   // 1024 * 64 B = 64 KB

  loss_main<<<NBLK, NTHR, 0, stream>>>(pred, gt, vis, P, tracks, partials);
  loss_final<<<1, NTHR, 0, stream>>>(partials, out);
}